// Round 11
// baseline (397.946 us; speedup 1.0000x reference)
//
#include <hip/hip_runtime.h>
#include <hip/hip_fp16.h>
#include <math.h>

#define NPTS 35937        // 33^3
#define HID 256
#define TPB 256

typedef __attribute__((ext_vector_type(8))) short short8;
typedef __attribute__((ext_vector_type(4))) float f32x4;

// ---------- helpers ----------
__device__ __forceinline__ float fast_tanh(float x) {
    float e = __expf(2.0f * x);
    return 1.0f - __fdividef(2.0f, e + 1.0f);
}

__device__ __forceinline__ short f2bf(float f) {   // RNE float->bf16
    union { float f; unsigned u; } v; v.f = f;
    unsigned r = (v.u + 0x7fffu + ((v.u >> 16) & 1u)) >> 16;
    return (short)r;
}

// HW packed f32x2 -> bf16x2 (RNE)
__device__ __forceinline__ unsigned cvt_pk_bf16(float a, float b) {
    unsigned r;
    asm("v_cvt_pk_bf16_f32 %0, %1, %2" : "=v"(r) : "v"(a), "v"(b));
    return r;
}

// ---------- workspace layout (bytes) ----------
// P      [0, 417792)            bf16 packed weights
// cells  [992896, 3090048)      fp16x4 duplicated-corner cells: 32^3 * 64 B
#define W1P_OFF 8192
#define W2P_OFF 73728
#define W3P_OFF 139264
#define W4P_OFF 204800
#define CELL_BYTE_OFF 992896

__global__ __launch_bounds__(256) void pack_weights_kernel(
    const float* __restrict__ W0, const float* __restrict__ W1,
    const float* __restrict__ W2, const float* __restrict__ W3,
    const float* __restrict__ W4, short* __restrict__ P)
{
    int id = blockIdx.x * 256 + threadIdx.x;
    if (id >= 26112) return;
    const float* W; int f, NT, KREAL, NROW; long pbase;
    if (id < 1024)       { W = W0; f = id;         NT = 16; KREAL = 11;  NROW = 256; pbase = 0; }
    else if (id < 9216)  { W = W1; f = id - 1024;  NT = 16; KREAL = 256; NROW = 256; pbase = W1P_OFF; }
    else if (id < 17408) { W = W2; f = id - 9216;  NT = 16; KREAL = 256; NROW = 256; pbase = W2P_OFF; }
    else if (id < 25600) { W = W3; f = id - 17408; NT = 16; KREAL = 256; NROW = 256; pbase = W3P_OFF; }
    else                 { W = W4; f = id - 25600; NT = 1;  KREAL = 256; NROW = 3;   pbase = W4P_OFF; }
    int lane = f & 63;
    int tile = f >> 6;
    int nt = tile % NT, kt = tile / NT;
    int n  = nt * 16 + (lane & 15);
    int k0 = kt * 32 + ((lane >> 4) & 3) * 8;
    short v[8];
    #pragma unroll
    for (int j = 0; j < 8; ++j) {
        int k = k0 + j;
        float x = (k < KREAL && n < NROW) ? W[k * NROW + n] : 0.0f;
        v[j] = f2bf(x);
    }
    *(short8*)(P + pbase + (long)f * 8) = *(short8*)v;
}

// ---------- fused MLP via MFMA: 32 rows/block, scatter epilogue (R10) ----------
#define HSTR 264

__global__ __launch_bounds__(256) void nilut_mfma_kernel(
    const float* __restrict__ param, const short* __restrict__ P,
    const float* __restrict__ b0, const float* __restrict__ b1,
    const float* __restrict__ b2, const float* __restrict__ b3,
    const float* __restrict__ b4, __half* __restrict__ cells)
{
    __shared__ short Hs[32][HSTR];
    __shared__ short Is[32][40];
    __shared__ float OB[32][4];

    const int t = threadIdx.x;
    const int pblock = blockIdx.x * 16;
    const int lane = t & 63;
    const int wid  = t >> 6;        // 0..3
    const int lr = lane & 15;
    const int hi = lane >> 4;       // 0..3
    const int k8 = hi * 8;

    if (t < 32) {
        int pn = pblock + (t >> 1);
        if (pn >= NPTS) pn = NPTS - 1;
        int v = t & 1;
        int ii = pn / 1089;
        int rem = pn - ii * 1089;
        int jj = rem / 33;
        int kk = rem - jj * 33;
        float r = kk * (1.0f / 32.0f);
        float g = jj * (1.0f / 32.0f);
        float b = ii * (1.0f / 32.0f);
        float lo = fminf(r, fminf(g, b));
        float hv = fmaxf(r, fmaxf(g, b));
        float mid = r + g + b - lo - hv;   // exact: multiples of 1/32
        Is[t][0] = f2bf(r); Is[t][1] = f2bf(g); Is[t][2] = f2bf(b);
        #pragma unroll
        for (int q = 0; q < 5; ++q)
            Is[t][3 + q] = (v == 0) ? f2bf(param[q]) : (short)0;
        Is[t][8] = f2bf(lo); Is[t][9] = f2bf(mid); Is[t][10] = f2bf(hv);
        #pragma unroll
        for (int q = 11; q < 40; ++q) Is[t][q] = (short)0;
    }
    __syncthreads();

    f32x4 acc[2][4];
    const int nbase = wid * 64 + hi * 4;

    // ---- layer 0: (K=32 padded) -> 256, relu ----
    {
        #pragma unroll
        for (int c = 0; c < 4; ++c) {
            float4 bv = *(const float4*)(b0 + nbase + c * 16);
            f32x4 in = {bv.x, bv.y, bv.z, bv.w};
            #pragma unroll
            for (int rt = 0; rt < 2; ++rt) acc[rt][c] = in;
        }
        short8 a[2], bfr[4];
        #pragma unroll
        for (int rt = 0; rt < 2; ++rt) a[rt] = *(const short8*)&Is[rt * 16 + lr][k8];
        #pragma unroll
        for (int c = 0; c < 4; ++c)
            bfr[c] = *(const short8*)(P + ((long)(wid * 4 + c) * 64 + lane) * 8);
        #pragma unroll
        for (int rt = 0; rt < 2; ++rt)
            #pragma unroll
            for (int c = 0; c < 4; ++c)
                acc[rt][c] = __builtin_amdgcn_mfma_f32_16x16x32_bf16(bfr[c], a[rt], acc[rt][c], 0, 0, 0);
        #pragma unroll
        for (int rt = 0; rt < 2; ++rt)
            #pragma unroll
            for (int c = 0; c < 4; ++c) {
                uint2 w;
                w.x = cvt_pk_bf16(fmaxf(acc[rt][c][0], 0.0f), fmaxf(acc[rt][c][1], 0.0f));
                w.y = cvt_pk_bf16(fmaxf(acc[rt][c][2], 0.0f), fmaxf(acc[rt][c][3], 0.0f));
                *(uint2*)&Hs[rt * 16 + lr][nbase + c * 16] = w;
            }
    }
    __syncthreads();

    // ---- layers 1..3: 256 -> 256, tanh ----
    const long loff[3] = {W1P_OFF, W2P_OFF, W3P_OFF};
    const float* bptr[3];
    bptr[0] = b1; bptr[1] = b2; bptr[2] = b3;
    for (int L = 0; L < 3; ++L) {
        const short* WL = P + loff[L];
        const float* bb = bptr[L];
        #pragma unroll
        for (int c = 0; c < 4; ++c) {
            float4 bv = *(const float4*)(bb + nbase + c * 16);
            f32x4 in = {bv.x, bv.y, bv.z, bv.w};
            #pragma unroll
            for (int rt = 0; rt < 2; ++rt) acc[rt][c] = in;
        }
        #pragma unroll
        for (int kt = 0; kt < 8; ++kt) {
            short8 a[2], bfr[4];
            #pragma unroll
            for (int rt = 0; rt < 2; ++rt)
                a[rt] = *(const short8*)&Hs[rt * 16 + lr][kt * 32 + k8];
            #pragma unroll
            for (int c = 0; c < 4; ++c)
                bfr[c] = *(const short8*)(WL + ((long)(kt * 16 + wid * 4 + c) * 64 + lane) * 8);
            #pragma unroll
            for (int rt = 0; rt < 2; ++rt)
                #pragma unroll
                for (int c = 0; c < 4; ++c)
                    acc[rt][c] = __builtin_amdgcn_mfma_f32_16x16x32_bf16(bfr[c], a[rt], acc[rt][c], 0, 0, 0);
        }
        __syncthreads();
        #pragma unroll
        for (int rt = 0; rt < 2; ++rt)
            #pragma unroll
            for (int c = 0; c < 4; ++c) {
                uint2 w;
                w.x = cvt_pk_bf16(fast_tanh(acc[rt][c][0]), fast_tanh(acc[rt][c][1]));
                w.y = cvt_pk_bf16(fast_tanh(acc[rt][c][2]), fast_tanh(acc[rt][c][3]));
                *(uint2*)&Hs[rt * 16 + lr][nbase + c * 16] = w;
            }
        __syncthreads();
    }

    // ---- layer 4: 256 -> 3; waves 0-1 cover rows 0..31 ----
    if (wid < 2) {
        float bv = (lr < 3) ? b4[lr] : 0.0f;
        f32x4 a4 = {bv, bv, bv, bv};
        const short* WL = P + W4P_OFF;
        #pragma unroll
        for (int kt = 0; kt < 8; ++kt) {
            short8 a = *(const short8*)&Hs[wid * 16 + lr][kt * 32 + k8];
            short8 b = *(const short8*)(WL + ((long)kt * 64 + lane) * 8);
            a4 = __builtin_amdgcn_mfma_f32_16x16x32_bf16(a, b, a4, 0, 0, 0);
        }
        if (lr < 3) {
            #pragma unroll
            for (int q = 0; q < 4; ++q)
                OB[wid * 16 + hi * 4 + q][lr] = a4[q];
        }
    }
    __syncthreads();

    // epilogue: point value -> fp16x4, scatter to all incident cell corners
    if (t < 16) {
        int n = pblock + t;
        if (n < NPTS) {
            int ii = n / 1089;
            int rem = n - ii * 1089;
            int jj = rem / 33;
            int kk = rem - jj * 33;
            float vr = OB[2 * t][0] - OB[2 * t + 1][0] + kk * (1.0f / 32.0f);
            float vg = OB[2 * t][1] - OB[2 * t + 1][1] + jj * (1.0f / 32.0f);
            float vb = OB[2 * t][2] - OB[2 * t + 1][2] + ii * (1.0f / 32.0f);
            union { __half h[4]; uint2 u; } pk;
            pk.h[0] = __float2half_rn(vr);
            pk.h[1] = __float2half_rn(vg);
            pk.h[2] = __float2half_rn(vb);
            pk.h[3] = __float2half_rn(0.0f);
            #pragma unroll
            for (int corner = 0; corner < 8; ++corner) {
                int dr = corner & 1, dg = (corner >> 1) & 1, db = corner >> 2;
                int cr = kk - dr, cg = jj - dg, cb = ii - db;
                if ((unsigned)cr < 32u && (unsigned)cg < 32u && (unsigned)cb < 32u) {
                    long cell = cb * 1024 + cg * 32 + cr;
                    *(uint2*)(cells + cell * 32 + corner * 4) = pk.u;
                }
            }
        }
    }
}

// ---------- trilinear apply (R9 body) + NONTEMPORAL gather loads ----------
// nt flag bypasses L1 allocation on the cell gathers -> takes them out of the
// L1 miss/fill (MSHR-limited) path, the suspected ~104 us wall.
#define LERP(a, b, f) fmaf((f), (b) - (a), (a))

__global__ __launch_bounds__(256) void apply_lut_kernel(
    const float* __restrict__ img, const __half* __restrict__ cells,
    float* __restrict__ out)
{
    const int NP = 2160 * 3840;
    int idx = blockIdx.x * blockDim.x + threadIdx.x;
    int p = idx * 4;
    if (p >= NP) return;

    float4 rv = *(const float4*)(img + p);
    float4 gv = *(const float4*)(img + NP + p);
    float4 bv = *(const float4*)(img + 2 * NP + p);

    float rr[4] = {rv.x, rv.y, rv.z, rv.w};
    float gg[4] = {gv.x, gv.y, gv.z, gv.w};
    float bb[4] = {bv.x, bv.y, bv.z, bv.w};
    float ox[4], oy[4], oz[4];

    #pragma unroll
    for (int u = 0; u < 4; ++u) {
        float sr = rr[u] * 32.0f, sg = gg[u] * 32.0f, sb = bb[u] * 32.0f;
        float fir = fminf(fmaxf(floorf(sr), 0.0f), 31.0f);
        float fig = fminf(fmaxf(floorf(sg), 0.0f), 31.0f);
        float fib = fminf(fmaxf(floorf(sb), 0.0f), 31.0f);
        float fr = sr - fir, fg = sg - fig, fb = sb - fib;
        int ir = (int)fir, ig = (int)fig, ib = (int)fib;

        const short8* cb = (const short8*)(cells + ((long)(ib * 1024 + ig * 32 + ir)) * 32);
        union { short8 s; __half h[8]; } u0, u1, u2, u3;
        u0.s = __builtin_nontemporal_load(cb + 0);
        u1.s = __builtin_nontemporal_load(cb + 1);
        u2.s = __builtin_nontemporal_load(cb + 2);
        u3.s = __builtin_nontemporal_load(cb + 3);

        float v00[3], v01[3], v10[3], v11[3];
        #pragma unroll
        for (int c = 0; c < 3; ++c) {
            v00[c] = LERP(__half2float(u0.h[c]), __half2float(u0.h[c + 4]), fr);
            v01[c] = LERP(__half2float(u1.h[c]), __half2float(u1.h[c + 4]), fr);
            v10[c] = LERP(__half2float(u2.h[c]), __half2float(u2.h[c + 4]), fr);
            v11[c] = LERP(__half2float(u3.h[c]), __half2float(u3.h[c + 4]), fr);
        }
        ox[u] = LERP(LERP(v00[0], v01[0], fg), LERP(v10[0], v11[0], fg), fb);
        oy[u] = LERP(LERP(v00[1], v01[1], fg), LERP(v10[1], v11[1], fg), fb);
        oz[u] = LERP(LERP(v00[2], v01[2], fg), LERP(v10[2], v11[2], fg), fb);
    }

    *(float4*)(out + p)          = make_float4(ox[0], ox[1], ox[2], ox[3]);
    *(float4*)(out + NP + p)     = make_float4(oy[0], oy[1], oy[2], oy[3]);
    *(float4*)(out + 2 * NP + p) = make_float4(oz[0], oz[1], oz[2], oz[3]);
}

extern "C" void kernel_launch(void* const* d_in, const int* in_sizes, int n_in,
                              void* d_out, int out_size, void* d_ws, size_t ws_size,
                              hipStream_t stream) {
    const float* img   = (const float*)d_in[0];
    const float* param = (const float*)d_in[1];
    const float* W0 = (const float*)d_in[2];
    const float* b0 = (const float*)d_in[3];
    const float* W1 = (const float*)d_in[4];
    const float* b1 = (const float*)d_in[5];
    const float* W2 = (const float*)d_in[6];
    const float* b2 = (const float*)d_in[7];
    const float* W3 = (const float*)d_in[8];
    const float* b3 = (const float*)d_in[9];
    const float* W4 = (const float*)d_in[10];
    const float* b4 = (const float*)d_in[11];

    short*  P     = (short*)d_ws;
    __half* cells = (__half*)((char*)d_ws + CELL_BYTE_OFF);
    float*  out   = (float*)d_out;

    hipLaunchKernelGGL(pack_weights_kernel, dim3(102), dim3(TPB), 0, stream,
                       W0, W1, W2, W3, W4, P);

    int lut_blocks = (NPTS + 15) / 16;     // 2247
    hipLaunchKernelGGL(nilut_mfma_kernel, dim3(lut_blocks), dim3(TPB), 0, stream,
                       param, P, b0, b1, b2, b3, b4, cells);

    const int NP = 2160 * 3840;
    int apply_blocks = (NP / 4 + TPB - 1) / TPB;   // 8100
    hipLaunchKernelGGL(apply_lut_kernel, dim3(apply_blocks), dim3(TPB), 0, stream,
                       img, cells, out);
}

// Round 12
// 132.080 us; speedup vs baseline: 3.0129x; 3.0129x over previous
//
#include <hip/hip_runtime.h>
#include <hip/hip_fp16.h>
#include <math.h>

#define NPTS 35937        // 33^3
#define HID 256
#define TPB 256

typedef __attribute__((ext_vector_type(8))) short short8;
typedef __attribute__((ext_vector_type(4))) float f32x4;

// ---------- helpers ----------
__device__ __forceinline__ float fast_tanh(float x) {
    float e = __expf(2.0f * x);
    return 1.0f - __fdividef(2.0f, e + 1.0f);
}

__device__ __forceinline__ short f2bf(float f) {   // RNE float->bf16
    union { float f; unsigned u; } v; v.f = f;
    unsigned r = (v.u + 0x7fffu + ((v.u >> 16) & 1u)) >> 16;
    return (short)r;
}

// HW packed f32x2 -> bf16x2 (RNE)
__device__ __forceinline__ unsigned cvt_pk_bf16(float a, float b) {
    unsigned r;
    asm("v_cvt_pk_bf16_f32 %0, %1, %2" : "=v"(r) : "v"(a), "v"(b));
    return r;
}

// ---------- workspace layout (bytes) ----------
// P      [0, 417792)            bf16 packed weights
// cells  [992896, 3090048)      fp16x4 duplicated-corner cells: 32^3 * 64 B
#define W1P_OFF 8192
#define W2P_OFF 73728
#define W3P_OFF 139264
#define W4P_OFF 204800
#define CELL_BYTE_OFF 992896

__global__ __launch_bounds__(256) void pack_weights_kernel(
    const float* __restrict__ W0, const float* __restrict__ W1,
    const float* __restrict__ W2, const float* __restrict__ W3,
    const float* __restrict__ W4, short* __restrict__ P)
{
    int id = blockIdx.x * 256 + threadIdx.x;
    if (id >= 26112) return;
    const float* W; int f, NT, KREAL, NROW; long pbase;
    if (id < 1024)       { W = W0; f = id;         NT = 16; KREAL = 11;  NROW = 256; pbase = 0; }
    else if (id < 9216)  { W = W1; f = id - 1024;  NT = 16; KREAL = 256; NROW = 256; pbase = W1P_OFF; }
    else if (id < 17408) { W = W2; f = id - 9216;  NT = 16; KREAL = 256; NROW = 256; pbase = W2P_OFF; }
    else if (id < 25600) { W = W3; f = id - 17408; NT = 16; KREAL = 256; NROW = 256; pbase = W3P_OFF; }
    else                 { W = W4; f = id - 25600; NT = 1;  KREAL = 256; NROW = 3;   pbase = W4P_OFF; }
    int lane = f & 63;
    int tile = f >> 6;
    int nt = tile % NT, kt = tile / NT;
    int n  = nt * 16 + (lane & 15);
    int k0 = kt * 32 + ((lane >> 4) & 3) * 8;
    short v[8];
    #pragma unroll
    for (int j = 0; j < 8; ++j) {
        int k = k0 + j;
        float x = (k < KREAL && n < NROW) ? W[k * NROW + n] : 0.0f;
        v[j] = f2bf(x);
    }
    *(short8*)(P + pbase + (long)f * 8) = *(short8*)v;
}

// ---------- fused MLP via MFMA: 32 rows/block, scatter epilogue ----------
#define HSTR 264

__global__ __launch_bounds__(256) void nilut_mfma_kernel(
    const float* __restrict__ param, const short* __restrict__ P,
    const float* __restrict__ b0, const float* __restrict__ b1,
    const float* __restrict__ b2, const float* __restrict__ b3,
    const float* __restrict__ b4, __half* __restrict__ cells)
{
    __shared__ short Hs[32][HSTR];
    __shared__ short Is[32][40];
    __shared__ float OB[32][4];

    const int t = threadIdx.x;
    const int pblock = blockIdx.x * 16;
    const int lane = t & 63;
    const int wid  = t >> 6;        // 0..3
    const int lr = lane & 15;
    const int hi = lane >> 4;       // 0..3
    const int k8 = hi * 8;

    if (t < 32) {
        int pn = pblock + (t >> 1);
        if (pn >= NPTS) pn = NPTS - 1;
        int v = t & 1;
        int ii = pn / 1089;
        int rem = pn - ii * 1089;
        int jj = rem / 33;
        int kk = rem - jj * 33;
        float r = kk * (1.0f / 32.0f);
        float g = jj * (1.0f / 32.0f);
        float b = ii * (1.0f / 32.0f);
        float lo = fminf(r, fminf(g, b));
        float hv = fmaxf(r, fmaxf(g, b));
        float mid = r + g + b - lo - hv;   // exact: multiples of 1/32
        Is[t][0] = f2bf(r); Is[t][1] = f2bf(g); Is[t][2] = f2bf(b);
        #pragma unroll
        for (int q = 0; q < 5; ++q)
            Is[t][3 + q] = (v == 0) ? f2bf(param[q]) : (short)0;
        Is[t][8] = f2bf(lo); Is[t][9] = f2bf(mid); Is[t][10] = f2bf(hv);
        #pragma unroll
        for (int q = 11; q < 40; ++q) Is[t][q] = (short)0;
    }
    __syncthreads();

    f32x4 acc[2][4];
    const int nbase = wid * 64 + hi * 4;

    // ---- layer 0: (K=32 padded) -> 256, relu ----
    {
        #pragma unroll
        for (int c = 0; c < 4; ++c) {
            float4 bv = *(const float4*)(b0 + nbase + c * 16);
            f32x4 in = {bv.x, bv.y, bv.z, bv.w};
            #pragma unroll
            for (int rt = 0; rt < 2; ++rt) acc[rt][c] = in;
        }
        short8 a[2], bfr[4];
        #pragma unroll
        for (int rt = 0; rt < 2; ++rt) a[rt] = *(const short8*)&Is[rt * 16 + lr][k8];
        #pragma unroll
        for (int c = 0; c < 4; ++c)
            bfr[c] = *(const short8*)(P + ((long)(wid * 4 + c) * 64 + lane) * 8);
        #pragma unroll
        for (int rt = 0; rt < 2; ++rt)
            #pragma unroll
            for (int c = 0; c < 4; ++c)
                acc[rt][c] = __builtin_amdgcn_mfma_f32_16x16x32_bf16(bfr[c], a[rt], acc[rt][c], 0, 0, 0);
        #pragma unroll
        for (int rt = 0; rt < 2; ++rt)
            #pragma unroll
            for (int c = 0; c < 4; ++c) {
                uint2 w;
                w.x = cvt_pk_bf16(fmaxf(acc[rt][c][0], 0.0f), fmaxf(acc[rt][c][1], 0.0f));
                w.y = cvt_pk_bf16(fmaxf(acc[rt][c][2], 0.0f), fmaxf(acc[rt][c][3], 0.0f));
                *(uint2*)&Hs[rt * 16 + lr][nbase + c * 16] = w;
            }
    }
    __syncthreads();

    // ---- layers 1..3: 256 -> 256, tanh ----
    const long loff[3] = {W1P_OFF, W2P_OFF, W3P_OFF};
    const float* bptr[3];
    bptr[0] = b1; bptr[1] = b2; bptr[2] = b3;
    for (int L = 0; L < 3; ++L) {
        const short* WL = P + loff[L];
        const float* bb = bptr[L];
        #pragma unroll
        for (int c = 0; c < 4; ++c) {
            float4 bv = *(const float4*)(bb + nbase + c * 16);
            f32x4 in = {bv.x, bv.y, bv.z, bv.w};
            #pragma unroll
            for (int rt = 0; rt < 2; ++rt) acc[rt][c] = in;
        }
        #pragma unroll
        for (int kt = 0; kt < 8; ++kt) {
            short8 a[2], bfr[4];
            #pragma unroll
            for (int rt = 0; rt < 2; ++rt)
                a[rt] = *(const short8*)&Hs[rt * 16 + lr][kt * 32 + k8];
            #pragma unroll
            for (int c = 0; c < 4; ++c)
                bfr[c] = *(const short8*)(WL + ((long)(kt * 16 + wid * 4 + c) * 64 + lane) * 8);
            #pragma unroll
            for (int rt = 0; rt < 2; ++rt)
                #pragma unroll
                for (int c = 0; c < 4; ++c)
                    acc[rt][c] = __builtin_amdgcn_mfma_f32_16x16x32_bf16(bfr[c], a[rt], acc[rt][c], 0, 0, 0);
        }
        __syncthreads();
        #pragma unroll
        for (int rt = 0; rt < 2; ++rt)
            #pragma unroll
            for (int c = 0; c < 4; ++c) {
                uint2 w;
                w.x = cvt_pk_bf16(fast_tanh(acc[rt][c][0]), fast_tanh(acc[rt][c][1]));
                w.y = cvt_pk_bf16(fast_tanh(acc[rt][c][2]), fast_tanh(acc[rt][c][3]));
                *(uint2*)&Hs[rt * 16 + lr][nbase + c * 16] = w;
            }
        __syncthreads();
    }

    // ---- layer 4: 256 -> 3; waves 0-1 cover rows 0..31 ----
    if (wid < 2) {
        float bv = (lr < 3) ? b4[lr] : 0.0f;
        f32x4 a4 = {bv, bv, bv, bv};
        const short* WL = P + W4P_OFF;
        #pragma unroll
        for (int kt = 0; kt < 8; ++kt) {
            short8 a = *(const short8*)&Hs[wid * 16 + lr][kt * 32 + k8];
            short8 b = *(const short8*)(WL + ((long)kt * 64 + lane) * 8);
            a4 = __builtin_amdgcn_mfma_f32_16x16x32_bf16(a, b, a4, 0, 0, 0);
        }
        if (lr < 3) {
            #pragma unroll
            for (int q = 0; q < 4; ++q)
                OB[wid * 16 + hi * 4 + q][lr] = a4[q];
        }
    }
    __syncthreads();

    // epilogue: point value -> fp16x4, scatter to all incident cell corners
    if (t < 16) {
        int n = pblock + t;
        if (n < NPTS) {
            int ii = n / 1089;
            int rem = n - ii * 1089;
            int jj = rem / 33;
            int kk = rem - jj * 33;
            float vr = OB[2 * t][0] - OB[2 * t + 1][0] + kk * (1.0f / 32.0f);
            float vg = OB[2 * t][1] - OB[2 * t + 1][1] + jj * (1.0f / 32.0f);
            float vb = OB[2 * t][2] - OB[2 * t + 1][2] + ii * (1.0f / 32.0f);
            union { __half h[4]; uint2 u; } pk;
            pk.h[0] = __float2half_rn(vr);
            pk.h[1] = __float2half_rn(vg);
            pk.h[2] = __float2half_rn(vb);
            pk.h[3] = __float2half_rn(0.0f);
            #pragma unroll
            for (int corner = 0; corner < 8; ++corner) {
                int dr = corner & 1, dg = (corner >> 1) & 1, db = corner >> 2;
                int cr = kk - dr, cg = jj - dg, cb = ii - db;
                if ((unsigned)cr < 32u && (unsigned)cg < 32u && (unsigned)cb < 32u) {
                    long cell = cb * 1024 + cg * 32 + cr;
                    *(uint2*)(cells + cell * 32 + corner * 4) = pk.u;
                }
            }
        }
    }
}

// ---------- trilinear apply (R9 body, plain cached loads) ----------
// Do NOT use nontemporal loads on the gathers: on gfx950 nt bypasses L1 AND
// L2 -> every gather goes to the HBM path (R11: 104 -> 345 us, FETCH 61 -> 436 MB).
#define LERP(a, b, f) fmaf((f), (b) - (a), (a))

__global__ __launch_bounds__(256) void apply_lut_kernel(
    const float* __restrict__ img, const __half* __restrict__ cells,
    float* __restrict__ out)
{
    const int NP = 2160 * 3840;
    int idx = blockIdx.x * blockDim.x + threadIdx.x;
    int p = idx * 4;
    if (p >= NP) return;

    float4 rv = *(const float4*)(img + p);
    float4 gv = *(const float4*)(img + NP + p);
    float4 bv = *(const float4*)(img + 2 * NP + p);

    float rr[4] = {rv.x, rv.y, rv.z, rv.w};
    float gg[4] = {gv.x, gv.y, gv.z, gv.w};
    float bb[4] = {bv.x, bv.y, bv.z, bv.w};
    float ox[4], oy[4], oz[4];

    #pragma unroll
    for (int u = 0; u < 4; ++u) {
        float sr = rr[u] * 32.0f, sg = gg[u] * 32.0f, sb = bb[u] * 32.0f;
        float fir = fminf(fmaxf(floorf(sr), 0.0f), 31.0f);
        float fig = fminf(fmaxf(floorf(sg), 0.0f), 31.0f);
        float fib = fminf(fmaxf(floorf(sb), 0.0f), 31.0f);
        float fr = sr - fir, fg = sg - fig, fb = sb - fib;
        int ir = (int)fir, ig = (int)fig, ib = (int)fib;

        const short8* cb = (const short8*)(cells + ((long)(ib * 1024 + ig * 32 + ir)) * 32);
        union { short8 s; __half h[8]; } u0, u1, u2, u3;
        u0.s = cb[0]; u1.s = cb[1]; u2.s = cb[2]; u3.s = cb[3];

        float v00[3], v01[3], v10[3], v11[3];
        #pragma unroll
        for (int c = 0; c < 3; ++c) {
            v00[c] = LERP(__half2float(u0.h[c]), __half2float(u0.h[c + 4]), fr);
            v01[c] = LERP(__half2float(u1.h[c]), __half2float(u1.h[c + 4]), fr);
            v10[c] = LERP(__half2float(u2.h[c]), __half2float(u2.h[c + 4]), fr);
            v11[c] = LERP(__half2float(u3.h[c]), __half2float(u3.h[c + 4]), fr);
        }
        ox[u] = LERP(LERP(v00[0], v01[0], fg), LERP(v10[0], v11[0], fg), fb);
        oy[u] = LERP(LERP(v00[1], v01[1], fg), LERP(v10[1], v11[1], fg), fb);
        oz[u] = LERP(LERP(v00[2], v01[2], fg), LERP(v10[2], v11[2], fg), fb);
    }

    *(float4*)(out + p)          = make_float4(ox[0], ox[1], ox[2], ox[3]);
    *(float4*)(out + NP + p)     = make_float4(oy[0], oy[1], oy[2], oy[3]);
    *(float4*)(out + 2 * NP + p) = make_float4(oz[0], oz[1], oz[2], oz[3]);
}

extern "C" void kernel_launch(void* const* d_in, const int* in_sizes, int n_in,
                              void* d_out, int out_size, void* d_ws, size_t ws_size,
                              hipStream_t stream) {
    const float* img   = (const float*)d_in[0];
    const float* param = (const float*)d_in[1];
    const float* W0 = (const float*)d_in[2];
    const float* b0 = (const float*)d_in[3];
    const float* W1 = (const float*)d_in[4];
    const float* b1 = (const float*)d_in[5];
    const float* W2 = (const float*)d_in[6];
    const float* b2 = (const float*)d_in[7];
    const float* W3 = (const float*)d_in[8];
    const float* b3 = (const float*)d_in[9];
    const float* W4 = (const float*)d_in[10];
    const float* b4 = (const float*)d_in[11];

    short*  P     = (short*)d_ws;
    __half* cells = (__half*)((char*)d_ws + CELL_BYTE_OFF);
    float*  out   = (float*)d_out;

    hipLaunchKernelGGL(pack_weights_kernel, dim3(102), dim3(TPB), 0, stream,
                       W0, W1, W2, W3, W4, P);

    int lut_blocks = (NPTS + 15) / 16;     // 2247
    hipLaunchKernelGGL(nilut_mfma_kernel, dim3(lut_blocks), dim3(TPB), 0, stream,
                       param, P, b0, b1, b2, b3, b4, cells);

    const int NP = 2160 * 3840;
    int apply_blocks = (NP / 4 + TPB - 1) / TPB;   // 8100
    hipLaunchKernelGGL(apply_lut_kernel, dim3(apply_blocks), dim3(TPB), 0, stream,
                       img, cells, out);
}